// Round 3
// baseline (186.443 us; speedup 1.0000x reference)
//
#include <hip/hip_runtime.h>

#define EPS 1e-5f
constexpr int B = 4, C = 64, H = 128, W = 256;
constexpr int Hg = 512, Wg = 1024;
constexpr int NC = 19;
constexpr int HW = H * W;      // 32768 pixels per (b,c) plane
constexpr int HW4 = HW / 4;    // 8192 packed-class dwords per batch

// ---------------- K1: downsample gt (stride 4), pack classes to u8, histogram -------
// 128 blocks x 256: thread -> 4 gt loads (stride 16B), 1 coalesced dword store.
// Each block covers 4 rows of ONE batch (32 blocks per batch). Per-block hist ->
// counts_pb[cid][blk] (transposed so the consumer reads int4-contiguous).
__global__ __launch_bounds__(256) void k_pack(const int* __restrict__ gt,
                                              unsigned int* __restrict__ gt_p,
                                              int* __restrict__ counts_pb) { // [NC][128]
  __shared__ int hist[NC];
  int t = threadIdx.x;
  if (t < NC) hist[t] = 0;
  __syncthreads();
  int R = blockIdx.x * 4 + (t >> 6);        // global row in [0,512) = b*H + h
  int ws = t & 63;                          // 4-pixel segment within the row
  int b = R >> 7, h = R & 127;
  const int* row = gt + (size_t)(b * Hg + h * 4) * Wg;
  unsigned int c0 = (unsigned int)row[(ws * 4 + 0) * 4];
  unsigned int c1 = (unsigned int)row[(ws * 4 + 1) * 4];
  unsigned int c2 = (unsigned int)row[(ws * 4 + 2) * 4];
  unsigned int c3 = (unsigned int)row[(ws * 4 + 3) * 4];
  gt_p[R * 64 + ws] = c0 | (c1 << 8) | (c2 << 16) | (c3 << 24);
  atomicAdd(&hist[c0], 1); atomicAdd(&hist[c1], 1);   // classes are in [0,19)
  atomicAdd(&hist[c2], 1); atomicAdd(&hist[c3], 1);
  __syncthreads();
  if (t < NC) counts_pb[t * 128 + blockIdx.x] = hist[t];
}

// ---------------- K2: per-(b,c,eighth) partial per-class sum/sumsq ------------------
// ds_add_f32 accumulators acc[cls*64+lane]: fire-and-forget (no RMW latency chain),
// bank = lane&31 for ANY class -> conflict-free. LDS 9.7 KB -> 8 blocks/CU.
__global__ __launch_bounds__(256) void k_stats(const float* __restrict__ x,
                                               const unsigned int* __restrict__ gt_p,
                                               float* __restrict__ sums_p,   // [19*B*C][8]
                                               float* __restrict__ sqs_p) {  // [19*B*C][8]
  __shared__ float accS[NC * 64];   // 4864 B
  __shared__ float accQ[NC * 64];   // 4864 B
  int t = threadIdx.x;
  for (int k = t; k < NC * 64; k += 256) { accS[k] = 0.f; accQ[k] = 0.f; }
  __syncthreads();
  int plane = blockIdx.x >> 3;       // b*C + c
  int e8 = blockIdx.x & 7;
  int b = plane >> 6, c = plane & 63;
  int lane = t & 63;

  const float4* xp = (const float4*)x + (size_t)plane * (HW / 4) + e8 * 1024;
  const unsigned int* gp = gt_p + (size_t)b * HW4 + e8 * 1024;
  for (int j = 0; j < 4; j++) {
    int i = j * 256 + t;
    float4 v = xp[i];
    unsigned int g = gp[i];
    int c0 = g & 255, c1 = (g >> 8) & 255, c2 = (g >> 16) & 255, c3 = g >> 24;
    atomicAdd(&accS[c0 * 64 + lane], v.x); atomicAdd(&accQ[c0 * 64 + lane], v.x * v.x);
    atomicAdd(&accS[c1 * 64 + lane], v.y); atomicAdd(&accQ[c1 * 64 + lane], v.y * v.y);
    atomicAdd(&accS[c2 * 64 + lane], v.z); atomicAdd(&accQ[c2 * 64 + lane], v.z * v.z);
    atomicAdd(&accS[c3 * 64 + lane], v.w); atomicAdd(&accQ[c3 * 64 + lane], v.w * v.w);
  }
  __syncthreads();

  // wave w reduces classes w, w+4, ... : 2 LDS reads + butterfly shuffles.
  int w = t >> 6;
  for (int k = w; k < NC; k += 4) {
    float s  = accS[k * 64 + lane];
    float qq = accQ[k * 64 + lane];
    for (int m = 32; m >= 1; m >>= 1) {
      s  += __shfl_xor(s, m, 64);
      qq += __shfl_xor(qq, m, 64);
    }
    if (lane == 0) {
      int e = (k * B + b) * C + c;
      sums_p[e * 8 + e8] = s;
      sqs_p [e * 8 + e8] = qq;
    }
  }
}

// ---------------- K3: fused params (threads 0..18) + apply --------------------------
__global__ __launch_bounds__(256) void k_apply(const float* __restrict__ x,
                                               const unsigned int* __restrict__ gt_p,
                                               const float* __restrict__ sums_p,
                                               const float* __restrict__ sqs_p,
                                               const int* __restrict__ counts_pb,
                                               const float* __restrict__ eps_mu,
                                               const float* __restrict__ eps_std,
                                               float* __restrict__ out) {
  __shared__ float2 tab[NC];
  int t = threadIdx.x;
  int plane = blockIdx.x >> 2;     // b*C + c
  int q = blockIdx.x & 3;
  int b = plane >> 6, c = plane & 63;
  const float4* xp = (const float4*)x + (size_t)plane * (HW / 4) + q * 2048;
  const unsigned int* gp = gt_p + (size_t)b * HW4 + q * 2048;
  float4* op = (float4*)out + (size_t)plane * (HW / 4) + q * 2048;

  // prefetch tile j=0 while params compute
  float4 v0 = xp[t];
  unsigned int g0 = gp[t];

  if (t < NC) {                    // redundant tiny per-(cid,c) param math
    float mean[B], stdv[B];
    float msum = 0.f, ssum = 0.f;
    for (int bb = 0; bb < B; bb++) {
      const int4* cp = (const int4*)&counts_pb[t * 128 + bb * 32];
      int isum = 0;
      for (int j = 0; j < 8; j++) { int4 cv = cp[j]; isum += cv.x + cv.y + cv.z + cv.w; }
      float n = isum > 0 ? (float)isum : 1.f;   // npx = where(npx==0, 1, npx)
      int e = (t * B + bb) * C + c;
      float4 sa = *(const float4*)&sums_p[e * 8];
      float4 sb = *(const float4*)&sums_p[e * 8 + 4];
      float4 qa = *(const float4*)&sqs_p [e * 8];
      float4 qb = *(const float4*)&sqs_p [e * 8 + 4];
      float s  = (sa.x + sa.y + sa.z + sa.w) + (sb.x + sb.y + sb.z + sb.w);
      float qq = (qa.x + qa.y + qa.z + qa.w) + (qb.x + qb.y + qb.z + qb.w);
      float m = s / n;
      float var = qq / n - m * m;               // biased (divide by npx), as reference
      var = var > 0.f ? var : 0.f;
      mean[bb] = m;
      stdv[bb] = sqrtf(var + EPS);
      msum += m; ssum += stdv[bb];
    }
    float mbar = msum * 0.25f, sbar = ssum * 0.25f;
    float vm = 0.f, vs = 0.f;
    for (int bb = 0; bb < B; bb++) {
      float dm = mean[bb] - mbar; vm += dm * dm;
      float ds = stdv[bb] - sbar; vs += ds * ds;
    }
    float sqvm = sqrtf(vm * (1.f / 3.f) + EPS);   // ddof=1 over B=4
    float sqvs = sqrtf(vs * (1.f / 3.f) + EPS);
    int e = (t * B + b) * C + c;
    float beta  = mean[b] + eps_mu[e]  * sqvm;
    float gamma = stdv[b] + eps_std[e] * sqvs;
    float sc = gamma / stdv[b];
    tab[t] = make_float2(sc, beta - mean[b] * sc);  // out = x*sc + shift
  }
  __syncthreads();

  {
    float2 a0 = tab[g0 & 255], a1 = tab[(g0 >> 8) & 255];
    float2 a2 = tab[(g0 >> 16) & 255], a3 = tab[g0 >> 24];
    float4 o;
    o.x = fmaf(v0.x, a0.x, a0.y);
    o.y = fmaf(v0.y, a1.x, a1.y);
    o.z = fmaf(v0.z, a2.x, a2.y);
    o.w = fmaf(v0.w, a3.x, a3.y);
    op[t] = o;
  }
  for (int j = 1; j < 8; j++) {
    int i = j * 256 + t;
    float4 v = xp[i];
    unsigned int g = gp[i];
    float2 a0 = tab[g & 255], a1 = tab[(g >> 8) & 255];
    float2 a2 = tab[(g >> 16) & 255], a3 = tab[g >> 24];
    float4 o;
    o.x = fmaf(v.x, a0.x, a0.y);
    o.y = fmaf(v.y, a1.x, a1.y);
    o.z = fmaf(v.z, a2.x, a2.y);
    o.w = fmaf(v.w, a3.x, a3.y);
    op[i] = o;
  }
}

extern "C" void kernel_launch(void* const* d_in, const int* in_sizes, int n_in,
                              void* d_out, int out_size, void* d_ws, size_t ws_size,
                              hipStream_t stream) {
  const float* x       = (const float*)d_in[0];
  const int*   gt      = (const int*)  d_in[1];
  const float* eps_mu  = (const float*)d_in[2];
  const float* eps_std = (const float*)d_in[3];
  float* out = (float*)d_out;

  // workspace layout (~442 KB, fully overwritten every call)
  char* ws = (char*)d_ws;
  unsigned int* gt_p     = (unsigned int*)(ws);           // 131072 B packed classes
  float*        sums_p   = (float*)(ws + 131072);         // 19*B*C*8*4 = 155648 B
  float*        sqs_p    = (float*)(ws + 286720);         // 155648 B
  int*          counts_pb= (int*)  (ws + 442368);         // 19*128*4 = 9728 B

  hipLaunchKernelGGL(k_pack,  dim3(B * H / 4), dim3(256), 0, stream, gt, gt_p, counts_pb);
  hipLaunchKernelGGL(k_stats, dim3(B * C * 8), dim3(256), 0, stream,
                     x, gt_p, sums_p, sqs_p);
  hipLaunchKernelGGL(k_apply, dim3(B * C * 4), dim3(256), 0, stream,
                     x, gt_p, sums_p, sqs_p, counts_pb, eps_mu, eps_std, out);
}

// Round 4
// 119.776 us; speedup vs baseline: 1.5566x; 1.5566x over previous
//
#include <hip/hip_runtime.h>

#define EPS 1e-5f
constexpr int B = 4, C = 64, H = 128, W = 256;
constexpr int Hg = 512, Wg = 1024;
constexpr int NC = 19;
constexpr int HW = H * W;      // 32768 pixels per (b,c) plane
constexpr int HW4 = HW / 4;    // 8192 packed-class dwords per batch

// ---------------- K1: downsample gt (stride 4), pack classes to u8, histogram -------
// 128 blocks x 256 threads; block = 4 rows of one batch. Per-block hist ->
// counts_pb[cid][128] (transposed, int4-friendly for the k_stats reducer).
__global__ __launch_bounds__(256) void k_pack(const int* __restrict__ gt,
                                              unsigned int* __restrict__ gt_p,
                                              int* __restrict__ counts_pb) { // [NC][128]
  __shared__ int hist[NC];
  int t = threadIdx.x;
  if (t < NC) hist[t] = 0;
  __syncthreads();
  int R = blockIdx.x * 4 + (t >> 6);        // global row in [0,512) = b*H + h
  int ws = t & 63;                          // 4-pixel segment within the row
  int b = R >> 7, h = R & 127;
  const int* row = gt + (size_t)(b * Hg + h * 4) * Wg;
  unsigned int c0 = (unsigned int)row[ws * 16 + 0];
  unsigned int c1 = (unsigned int)row[ws * 16 + 4];
  unsigned int c2 = (unsigned int)row[ws * 16 + 8];
  unsigned int c3 = (unsigned int)row[ws * 16 + 12];
  gt_p[R * 64 + ws] = c0 | (c1 << 8) | (c2 << 16) | (c3 << 24);
  atomicAdd(&hist[c0], 1); atomicAdd(&hist[c1], 1);   // classes are in [0,19)
  atomicAdd(&hist[c2], 1); atomicAdd(&hist[c3], 1);
  __syncthreads();
  if (t < NC) counts_pb[t * 128 + blockIdx.x] = hist[t];
}

// ---------------- K2: per-(b,c,quarter) per-class sum/sumsq in REGISTERS ------------
// 19 (sum,sq) register accumulators per thread, fully-unrolled compare+select.
// No LDS in the hot loop (round-3 lesson: ds_add_f32 throughput is terrible).
// Butterfly-shuffle reduction; each wave's lane 0 stores 19 float2 partials.
__global__ __launch_bounds__(256, 4) void k_stats(const float* __restrict__ x,
                                                  const unsigned int* __restrict__ gt_p,
                                                  const int* __restrict__ counts_pb,
                                                  float2* __restrict__ par,   // [19*B*C][16]
                                                  int* __restrict__ counts) { // [B*NC]
  int t = threadIdx.x;
  int plane = blockIdx.x >> 2;       // b*C + c
  int q = blockIdx.x & 3;
  int b = plane >> 6, c = plane & 63;

  // 4 designated blocks (c==0,q==0): reduce k_pack's per-block hists -> counts[b][cls]
  if (c == 0 && q == 0 && t < NC) {
    const int4* cp = (const int4*)&counts_pb[t * 128 + b * 32];
    int s = 0;
#pragma unroll
    for (int j = 0; j < 8; j++) { int4 cv = cp[j]; s += cv.x + cv.y + cv.z + cv.w; }
    counts[b * NC + t] = s;
  }

  float accS[NC], accQ[NC];
#pragma unroll
  for (int k = 0; k < NC; k++) { accS[k] = 0.f; accQ[k] = 0.f; }

  const float4* xp = (const float4*)x + (size_t)plane * (HW / 4) + q * 2048;
  const unsigned int* gp = gt_p + (size_t)b * HW4 + q * 2048;
  for (int j = 0; j < 8; j++) {
    int i = j * 256 + t;
    float4 v = xp[i];
    unsigned int g = gp[i];
    int c0 = g & 255, c1 = (g >> 8) & 255, c2 = (g >> 16) & 255, c3 = g >> 24;
#pragma unroll
    for (int k = 0; k < NC; k++) {
      float m0 = (c0 == k) ? v.x : 0.f;
      float m1 = (c1 == k) ? v.y : 0.f;
      float m2 = (c2 == k) ? v.z : 0.f;
      float m3 = (c3 == k) ? v.w : 0.f;
      accS[k] += (m0 + m1) + (m2 + m3);
      accQ[k] += fmaf(m0, m0, fmaf(m1, m1, fmaf(m2, m2, m3 * m3)));
    }
  }

  // butterfly across the 64 lanes; all lanes end with wave totals
#pragma unroll
  for (int k = 0; k < NC; k++) {
    float s = accS[k], qq = accQ[k];
    for (int m = 32; m >= 1; m >>= 1) {
      s  += __shfl_xor(s, m, 64);
      qq += __shfl_xor(qq, m, 64);
    }
    accS[k] = s; accQ[k] = qq;
  }
  if ((t & 63) == 0) {
    int w = t >> 6;
#pragma unroll
    for (int k = 0; k < NC; k++) {
      int e = (k * B + b) * C + c;
      par[e * 16 + q * 4 + w] = make_float2(accS[k], accQ[k]);
    }
  }
}

// ---------------- K3: fused params (threads 0..18) + apply --------------------------
__global__ __launch_bounds__(256) void k_apply(const float* __restrict__ x,
                                               const unsigned int* __restrict__ gt_p,
                                               const float2* __restrict__ par,
                                               const int* __restrict__ counts,
                                               const float* __restrict__ eps_mu,
                                               const float* __restrict__ eps_std,
                                               float* __restrict__ out) {
  __shared__ float2 tab[NC];
  int t = threadIdx.x;
  int plane = blockIdx.x >> 2;     // b*C + c
  int q = blockIdx.x & 3;
  int b = plane >> 6, c = plane & 63;
  const float4* xp = (const float4*)x + (size_t)plane * (HW / 4) + q * 2048;
  const unsigned int* gp = gt_p + (size_t)b * HW4 + q * 2048;
  float4* op = (float4*)out + (size_t)plane * (HW / 4) + q * 2048;

  // prefetch tile j=0 while params compute
  float4 v0 = xp[t];
  unsigned int g0 = gp[t];

  if (t < NC) {                    // redundant tiny per-(cid,c) param math
    float mean[B], stdv[B];
    float msum = 0.f, ssum = 0.f;
#pragma unroll
    for (int bb = 0; bb < B; bb++) {
      int cnt = counts[bb * NC + t];
      float n = cnt > 0 ? (float)cnt : 1.f;     // npx = where(npx==0, 1, npx)
      const float4* pp = (const float4*)&par[((t * B + bb) * C + c) * 16];
      float s = 0.f, qq = 0.f;
#pragma unroll
      for (int j = 0; j < 8; j++) { float4 p = pp[j]; s += p.x + p.z; qq += p.y + p.w; }
      float m = s / n;
      float var = qq / n - m * m;               // biased (divide by npx), as reference
      var = var > 0.f ? var : 0.f;
      mean[bb] = m;
      stdv[bb] = sqrtf(var + EPS);
      msum += m; ssum += stdv[bb];
    }
    float mbar = msum * 0.25f, sbar = ssum * 0.25f;
    float vm = 0.f, vs = 0.f;
#pragma unroll
    for (int bb = 0; bb < B; bb++) {
      float dm = mean[bb] - mbar; vm += dm * dm;
      float ds = stdv[bb] - sbar; vs += ds * ds;
    }
    float sqvm = sqrtf(vm * (1.f / 3.f) + EPS);   // ddof=1 over B=4
    float sqvs = sqrtf(vs * (1.f / 3.f) + EPS);
    int e = (t * B + b) * C + c;
    float beta  = mean[b] + eps_mu[e]  * sqvm;
    float gamma = stdv[b] + eps_std[e] * sqvs;
    float sc = gamma / stdv[b];
    tab[t] = make_float2(sc, beta - mean[b] * sc);  // out = x*sc + shift
  }
  __syncthreads();

  {
    float2 a0 = tab[g0 & 255], a1 = tab[(g0 >> 8) & 255];
    float2 a2 = tab[(g0 >> 16) & 255], a3 = tab[g0 >> 24];
    float4 o;
    o.x = fmaf(v0.x, a0.x, a0.y);
    o.y = fmaf(v0.y, a1.x, a1.y);
    o.z = fmaf(v0.z, a2.x, a2.y);
    o.w = fmaf(v0.w, a3.x, a3.y);
    op[t] = o;
  }
  for (int j = 1; j < 8; j++) {
    int i = j * 256 + t;
    float4 v = xp[i];
    unsigned int g = gp[i];
    float2 a0 = tab[g & 255], a1 = tab[(g >> 8) & 255];
    float2 a2 = tab[(g >> 16) & 255], a3 = tab[g >> 24];
    float4 o;
    o.x = fmaf(v.x, a0.x, a0.y);
    o.y = fmaf(v.y, a1.x, a1.y);
    o.z = fmaf(v.z, a2.x, a2.y);
    o.w = fmaf(v.w, a3.x, a3.y);
    op[i] = o;
  }
}

extern "C" void kernel_launch(void* const* d_in, const int* in_sizes, int n_in,
                              void* d_out, int out_size, void* d_ws, size_t ws_size,
                              hipStream_t stream) {
  const float* x       = (const float*)d_in[0];
  const int*   gt      = (const int*)  d_in[1];
  const float* eps_mu  = (const float*)d_in[2];
  const float* eps_std = (const float*)d_in[3];
  float* out = (float*)d_out;

  // workspace layout (~764 KB, fully overwritten every call)
  char* ws = (char*)d_ws;
  unsigned int* gt_p     = (unsigned int*)(ws);           // 131072 B packed classes
  int*          counts_pb= (int*)   (ws + 131072);        // 19*128*4 = 9728 B
  int*          counts   = (int*)   (ws + 140800);        // 304 B (pad to 16B-multiple)
  float2*       par      = (float2*)(ws + 141104);        // 19*B*C*16*8 = 622592 B

  hipLaunchKernelGGL(k_pack,  dim3(B * H / 4), dim3(256), 0, stream, gt, gt_p, counts_pb);
  hipLaunchKernelGGL(k_stats, dim3(B * C * 4), dim3(256), 0, stream,
                     x, gt_p, counts_pb, par, counts);
  hipLaunchKernelGGL(k_apply, dim3(B * C * 4), dim3(256), 0, stream,
                     x, gt_p, par, counts, eps_mu, eps_std, out);
}